// Round 9
// baseline (118.665 us; speedup 1.0000x reference)
//
#include <hip/hip_runtime.h>

// VectorQuantizer round 9: fp8-e4m3 scan (emb prescaled x256), 32 waves/CU.
// x [32,64,4096] f32, emb [512,64] f32. N = 131072 rows (n = b*4096+t), D=64, K=512.
// prep: emb*256 -> fp8 MFMA-fragment table (32KB, [ct][lane] 16B = both K-halves)
//       + ctab[k] = 4 - ||e_k||^2/2 ; zero loss acc + ticket.
// main: 512 blocks x 512 thr (8 waves, 32 rows/wave). Stage frag+ctab to LDS
//   (36KB -> 4 blocks/CU). Scan all 512 cods: 1 ds_read_b128 + 4 fp8-MFMA per
//   2 cods; score v = dot/256 + ck, low-10-mantissa keyed fmax -> argmin with
//   first-min tie-break. Epilogue: exact fp32 gather + fused loss; last block
//   (ticket) writes the final loss. No separate finalize kernel.
// out[0..N*64) = emb[argmin][:] fp32 exact; out[N*64] = 1.25*mean((q-x_lin)^2).

#define VQ_OUTQ 8388608

typedef __attribute__((ext_vector_type(4))) float f32x4;

__global__ __launch_bounds__(256) void vq_prep(
    const float* __restrict__ emb,
    ulonglong2* __restrict__ frag,  // 2048 slots x 16B: [ct*64+lane] = {kc0,kc1}
    float* __restrict__ ctab,       // 512: 4 - ||e_k||^2/2
    double* __restrict__ lacc,
    unsigned* __restrict__ cnt)
{
    const int s = blockIdx.x * 256 + threadIdx.x;   // 0..2047
    const int ct = s >> 6, lane = s & 63;
    const int m = lane & 15, quad = lane >> 4;
    // B[k][col=ct*16+m], k = kc*32 + quad*8 + j, value = emb*256 -> fp8
    const float* __restrict__ er = emb + (ct * 16 + m) * 64 + quad * 8;
    float4 p0 = *(const float4*)er;          // kc0 j=0..3
    float4 p1 = *(const float4*)(er + 4);    // kc0 j=4..7
    float4 p2 = *(const float4*)(er + 32);   // kc1 j=0..3
    float4 p3 = *(const float4*)(er + 36);   // kc1 j=4..7
    int u0 = __builtin_amdgcn_cvt_pk_fp8_f32(p0.x * 256.f, p0.y * 256.f, 0, 0);
    u0     = __builtin_amdgcn_cvt_pk_fp8_f32(p0.z * 256.f, p0.w * 256.f, u0, 1);
    int u1 = __builtin_amdgcn_cvt_pk_fp8_f32(p1.x * 256.f, p1.y * 256.f, 0, 0);
    u1     = __builtin_amdgcn_cvt_pk_fp8_f32(p1.z * 256.f, p1.w * 256.f, u1, 1);
    int u2 = __builtin_amdgcn_cvt_pk_fp8_f32(p2.x * 256.f, p2.y * 256.f, 0, 0);
    u2     = __builtin_amdgcn_cvt_pk_fp8_f32(p2.z * 256.f, p2.w * 256.f, u2, 1);
    int u3 = __builtin_amdgcn_cvt_pk_fp8_f32(p3.x * 256.f, p3.y * 256.f, 0, 0);
    u3     = __builtin_amdgcn_cvt_pk_fp8_f32(p3.z * 256.f, p3.w * 256.f, u3, 1);
    ulonglong2 w;
    w.x = (unsigned long long)(unsigned)u0 | ((unsigned long long)(unsigned)u1 << 32);
    w.y = (unsigned long long)(unsigned)u2 | ((unsigned long long)(unsigned)u3 << 32);
    frag[s] = w;

    if (s < 512) {
        const float4* __restrict__ e4 = (const float4*)emb + s * 16;
        float c = 0.f;
        #pragma unroll
        for (int i = 0; i < 16; ++i) {
            float4 e = e4[i];
            c = fmaf(e.x, e.x, c); c = fmaf(e.y, e.y, c);
            c = fmaf(e.z, e.z, c); c = fmaf(e.w, e.w, c);
        }
        ctab[s] = fmaf(-0.5f, c, 4.0f);
    }
    if (s == 1024) { *lacc = 0.0; *cnt = 0u; }
}

// ---- main ----------------------------------------------------------------
__global__ __launch_bounds__(512, 8) void vq_main(
    const float* __restrict__ x,
    const float* __restrict__ emb,
    const ulonglong2* __restrict__ frag,
    const float* __restrict__ ctab,
    float* __restrict__ qout,
    double* __restrict__ lacc,
    unsigned* __restrict__ cnt)
{
    __shared__ __align__(16) ulonglong2 sfrag[2048];   // 32768 B
    __shared__ float cks[512];                         // 2048 B
    __shared__ int idxs[8][32];                        // wave-private
    __shared__ float wsum[8];

    const int tid  = threadIdx.x;
    const int lane = tid & 63, wave = tid >> 6;
    const int m = lane & 15, quad = lane >> 4;

    const int rowbase = blockIdx.x * 256 + wave * 32;   // 32 rows/wave
    const int b = rowbase >> 12, t = rowbase & 4095;

    // ---- stage frag table + ctab into LDS (linear, conflict-free)
    #pragma unroll
    for (int i = 0; i < 4; ++i) {
        const int s = i * 512 + tid;
        sfrag[s] = frag[s];
    }
    cks[tid] = ctab[tid];
    __syncthreads();

    // ---- A-frags: x[b, d, t+row] direct global -> fp8 (x unscaled)
    unsigned long long a[2][2];
    {
        const float* __restrict__ xa = x + (size_t)b * 262144 + t + m;
        #pragma unroll
        for (int rt = 0; rt < 2; ++rt) {
            #pragma unroll
            for (int kc = 0; kc < 2; ++kc) {
                const float* __restrict__ p =
                    xa + rt * 16 + (size_t)(kc * 32 + quad * 8) * 4096;
                float f[8];
                #pragma unroll
                for (int j = 0; j < 8; ++j) f[j] = p[(size_t)j * 4096];
                int u0 = __builtin_amdgcn_cvt_pk_fp8_f32(f[0], f[1], 0, 0);
                u0     = __builtin_amdgcn_cvt_pk_fp8_f32(f[2], f[3], u0, 1);
                int u1 = __builtin_amdgcn_cvt_pk_fp8_f32(f[4], f[5], 0, 0);
                u1     = __builtin_amdgcn_cvt_pk_fp8_f32(f[6], f[7], u1, 1);
                a[rt][kc] = (unsigned long long)(unsigned)u0
                          | ((unsigned long long)(unsigned)u1 << 32);
            }
        }
    }

    // ---- scan 512 cods from LDS: fp8 MFMA + mantissa-keyed fmax
    float best[2][4];
    #pragma unroll
    for (int rt = 0; rt < 2; ++rt)
        #pragma unroll
        for (int r = 0; r < 4; ++r) best[rt][r] = 0.f;   // all real keys > 3

    const float S = 1.0f / 256.0f;
    #pragma unroll 2
    for (int g = 0; g < 16; ++g) {
        const int ct0 = 2 * g, ct1 = 2 * g + 1;
        ulonglong2 B0 = sfrag[ct0 * 64 + lane];
        ulonglong2 B1 = sfrag[ct1 * 64 + lane];
        const float c0 = cks[(ct0 << 4) + m];
        const float c1 = cks[(ct1 << 4) + m];
        const unsigned f0 = 1023u - (unsigned)((ct0 << 4) + m);
        const unsigned f1 = 1023u - (unsigned)((ct1 << 4) + m);
        #pragma unroll
        for (int rt = 0; rt < 2; ++rt) {
            f32x4 p = {0.f, 0.f, 0.f, 0.f}, q = {0.f, 0.f, 0.f, 0.f};
            p = __builtin_amdgcn_mfma_f32_16x16x32_fp8_fp8((long)a[rt][0], (long)B0.x, p, 0, 0, 0);
            p = __builtin_amdgcn_mfma_f32_16x16x32_fp8_fp8((long)a[rt][1], (long)B0.y, p, 0, 0, 0);
            q = __builtin_amdgcn_mfma_f32_16x16x32_fp8_fp8((long)a[rt][0], (long)B1.x, q, 0, 0, 0);
            q = __builtin_amdgcn_mfma_f32_16x16x32_fp8_fp8((long)a[rt][1], (long)B1.y, q, 0, 0, 0);
            #pragma unroll
            for (int r = 0; r < 4; ++r) {
                float v0 = fmaf(p[r], S, c0);
                float v1 = fmaf(q[r], S, c1);
                float k0 = __uint_as_float((__float_as_uint(v0) & 0xFFFFFC00u) | f0);
                float k1 = __uint_as_float((__float_as_uint(v1) & 0xFFFFFC00u) | f1);
                best[rt][r] = fmaxf(best[rt][r], fmaxf(k0, k1));   // v_max3
            }
        }
    }

    // ---- cross-m max-reduce; idx from winner's mantissa
    #pragma unroll
    for (int rt = 0; rt < 2; ++rt) {
        #pragma unroll
        for (int r = 0; r < 4; ++r) {
            float bv = best[rt][r];
            #pragma unroll
            for (int mm = 1; mm < 16; mm <<= 1)
                bv = fmaxf(bv, __shfl_xor(bv, mm, 64));
            if (m == 0)
                idxs[wave][rt * 16 + (quad << 2) + r] =
                    1023 - (int)(__float_as_uint(bv) & 1023u);
        }
    }
    // no barrier: idxs wave-private, DS in-order per wave

    // ---- epilogue: wave's 32 rows = 8 KB contiguous; fused loss vs linear x
    {
        const float4* __restrict__ x4 = (const float4*)x + (size_t)rowbase * 16;
        float4* __restrict__ q4 = (float4*)qout + (size_t)rowbase * 16;
        const float4* __restrict__ e4 = (const float4*)emb;
        float ls = 0.f;
        #pragma unroll
        for (int j = 0; j < 8; ++j) {
            const int e = j * 64 + lane;       // float4 units, 0..511
            const int idx = idxs[wave][e >> 4];
            float4 q  = e4[idx * 16 + (e & 15)];
            float4 xr = x4[e];
            q4[e] = q;
            float dx = q.x - xr.x, dy = q.y - xr.y;
            float dz = q.z - xr.z, dw = q.w - xr.w;
            ls = fmaf(dx, dx, ls); ls = fmaf(dy, dy, ls);
            ls = fmaf(dz, dz, ls); ls = fmaf(dw, dw, ls);
        }
        #pragma unroll
        for (int off = 32; off > 0; off >>= 1)
            ls += __shfl_down(ls, off, 64);
        if (lane == 0) wsum[wave] = ls;
    }
    __syncthreads();

    // ---- loss: block partial -> device atomic; ticketed last block finishes
    if (tid == 0) {
        double s = 0.0;
        #pragma unroll
        for (int w = 0; w < 8; ++w) s += (double)wsum[w];
        atomicAdd(lacc, s);
        __threadfence();
        unsigned tk = atomicAdd(cnt, 1u);
        if (tk == 511u) {
            double tot = atomicAdd(lacc, 0.0);   // all 512 adds complete
            qout[VQ_OUTQ] = (float)(1.25 * tot / 8388608.0);
        }
    }
}

extern "C" void kernel_launch(void* const* d_in, const int* in_sizes, int n_in,
                              void* d_out, int out_size, void* d_ws, size_t ws_size,
                              hipStream_t stream)
{
    const float* x   = (const float*)d_in[0];
    const float* emb = (const float*)d_in[1];
    float* out = (float*)d_out;

    ulonglong2* frag = (ulonglong2*)d_ws;                    // 32768 B
    float*  ctab = (float*)((char*)d_ws + 32768);            // 2048 B
    double* lacc = (double*)((char*)d_ws + 32768 + 2048);    // 8 B
    unsigned* cnt = (unsigned*)((char*)d_ws + 32768 + 2064); // 4 B

    vq_prep<<<dim3(8), dim3(256), 0, stream>>>(emb, frag, ctab, lacc, cnt);
    vq_main<<<dim3(512), dim3(512), 0, stream>>>(x, emb, frag, ctab, out, lacc, cnt);
}

// Round 10
// 112.520 us; speedup vs baseline: 1.0546x; 1.0546x over previous
//
#include <hip/hip_runtime.h>

// VectorQuantizer round 10: R8 bf16 scan in 1024-thread blocks (32 waves/CU).
// x [32,64,4096] f32, emb [512,64] f32. N = 131072 rows (n = b*4096+t), D=64, K=512.
// prep: emb -> bf16 MFMA-fragment table (64KB) + ctab[k] = 4 - ||e_k||^2/2.
// main: 256 blocks x 1024 thr (16 waves, 32 rows/wave). Stage frag+ctab to LDS
//   once per block (70KB -> 2 blocks/CU = 32 waves/CU), scan all 512 cods via
//   mantissa-keyed fmax (low 10 bits = 1023-cod -> argmax == first-min argmin).
//   Epilogue: exact fp32 gather + fused loss; ticketed last block writes loss.
// out[0..N*64) = emb[argmin][:] fp32 exact; out[N*64] = 1.25*mean((q-x_lin)^2).

#define VQ_OUTQ 8388608

typedef __attribute__((ext_vector_type(8))) short short8;
typedef __attribute__((ext_vector_type(4))) float f32x4;

__device__ __forceinline__ unsigned pk_bf16(float a, float b) {
    union { float f; unsigned u; } x, y; x.f = a; y.f = b;
    return ((y.u + 0x8000u) & 0xFFFF0000u) | ((x.u + 0x8000u) >> 16);
}

// ---- prep: fragment table + score-bias table + zero loss acc/ticket ------
__global__ __launch_bounds__(256) void vq_prep(
    const float* __restrict__ emb,
    short8* __restrict__ frag,      // 4096 slots x 16B
    float* __restrict__ ctab,       // 512: 4 - ||e_k||^2 / 2
    double* __restrict__ lacc,
    unsigned* __restrict__ cnt)
{
    const int s = blockIdx.x * 256 + threadIdx.x;   // 0..4095
    const int l = s & 63, kc = (s >> 6) & 1, ct = s >> 7;
    const int qs = l >> 4, ms = l & 15;
    const float* __restrict__ er = emb + (ct * 16 + ms) * 64 + kc * 32 + qs * 8;
    float4 p0 = *(const float4*)er;
    float4 p1 = *(const float4*)(er + 4);
    union { short8 s8; unsigned u[4]; } w;
    w.u[0] = pk_bf16(p0.x, p0.y); w.u[1] = pk_bf16(p0.z, p0.w);
    w.u[2] = pk_bf16(p1.x, p1.y); w.u[3] = pk_bf16(p1.z, p1.w);
    frag[s] = w.s8;

    if (s < 512) {
        const float4* __restrict__ e4 = (const float4*)emb + s * 16;
        float c = 0.f;
        #pragma unroll
        for (int i = 0; i < 16; ++i) {
            float4 e = e4[i];
            c = fmaf(e.x, e.x, c); c = fmaf(e.y, e.y, c);
            c = fmaf(e.z, e.z, c); c = fmaf(e.w, e.w, c);
        }
        ctab[s] = fmaf(-0.5f, c, 4.0f);
    }
    if (s == 1024) { *lacc = 0.0; *cnt = 0u; }
}

// ---- main ----------------------------------------------------------------
__global__ __launch_bounds__(1024, 8) void vq_main(
    const float* __restrict__ x,
    const float* __restrict__ emb,
    const short8* __restrict__ frag,
    const float* __restrict__ ctab,
    float* __restrict__ qout,
    double* __restrict__ lacc,
    unsigned* __restrict__ cnt)
{
    __shared__ __align__(16) short8 sfrag[4096];   // 65536 B
    __shared__ float cks[512];                     // 2048 B
    __shared__ int idxs[16][32];                   // wave-private
    __shared__ float wsum[16];

    const int tid  = threadIdx.x;
    const int lane = tid & 63, wave = tid >> 6;
    const int m = lane & 15, quad = lane >> 4;

    const int rowbase = blockIdx.x * 512 + wave * 32;   // 32 rows/wave
    const int b = rowbase >> 12, t = rowbase & 4095;

    // ---- stage frag table + ctab into LDS (linear, conflict-free)
    #pragma unroll
    for (int i = 0; i < 4; ++i) {
        const int s = i * 1024 + tid;
        sfrag[s] = frag[s];
    }
    if (tid < 512) cks[tid] = ctab[tid];
    __syncthreads();

    // ---- A-frags: x[b, d, t+row] direct global -> bf16
    short8 a[2][2];
    {
        const float* __restrict__ xa = x + (size_t)b * 262144 + t + m;
        #pragma unroll
        for (int rt = 0; rt < 2; ++rt) {
            #pragma unroll
            for (int kc = 0; kc < 2; ++kc) {
                const float* __restrict__ p =
                    xa + rt * 16 + (size_t)(kc * 32 + quad * 8) * 4096;
                float f[8];
                #pragma unroll
                for (int j = 0; j < 8; ++j) f[j] = p[(size_t)j * 4096];
                union { short8 s8; unsigned u[4]; } w;
                w.u[0] = pk_bf16(f[0], f[1]); w.u[1] = pk_bf16(f[2], f[3]);
                w.u[2] = pk_bf16(f[4], f[5]); w.u[3] = pk_bf16(f[6], f[7]);
                a[rt][kc] = w.s8;
            }
        }
    }

    // ---- scan all 512 cods from LDS: mantissa-keyed fmax
    float best[2][4];
    #pragma unroll
    for (int rt = 0; rt < 2; ++rt)
        #pragma unroll
        for (int r = 0; r < 4; ++r) best[rt][r] = 0.f;   // all real keys > 3

    #pragma unroll 4
    for (int ct = 0; ct < 32; ++ct) {
        short8 b0 = sfrag[ct * 128 + lane];
        short8 b1 = sfrag[ct * 128 + 64 + lane];
        const int cod = (ct << 4) + m;
        const float ck = cks[cod];
        const unsigned fk = 1023u - (unsigned)cod;
        #pragma unroll
        for (int rt = 0; rt < 2; ++rt) {
            f32x4 p = {0.f, 0.f, 0.f, 0.f};
            p = __builtin_amdgcn_mfma_f32_16x16x32_bf16(a[rt][0], b0, p, 0, 0, 0);
            p = __builtin_amdgcn_mfma_f32_16x16x32_bf16(a[rt][1], b1, p, 0, 0, 0);
            #pragma unroll
            for (int r = 0; r < 4; ++r) {
                float v = p[r] + ck;
                float k = __uint_as_float((__float_as_uint(v) & 0xFFFFFC00u) | fk);
                best[rt][r] = fmaxf(best[rt][r], k);
            }
        }
    }

    // ---- cross-m max-reduce; idx from winner's mantissa
    #pragma unroll
    for (int rt = 0; rt < 2; ++rt) {
        #pragma unroll
        for (int r = 0; r < 4; ++r) {
            float bv = best[rt][r];
            #pragma unroll
            for (int mm = 1; mm < 16; mm <<= 1)
                bv = fmaxf(bv, __shfl_xor(bv, mm, 64));
            if (m == 0)
                idxs[wave][rt * 16 + (quad << 2) + r] =
                    1023 - (int)(__float_as_uint(bv) & 1023u);
        }
    }
    // no barrier: idxs wave-private, DS in-order per wave

    // ---- epilogue: wave's 32 rows = 8 KB contiguous; fused loss vs linear x
    {
        const float4* __restrict__ x4 = (const float4*)x + (size_t)rowbase * 16;
        float4* __restrict__ q4 = (float4*)qout + (size_t)rowbase * 16;
        const float4* __restrict__ e4 = (const float4*)emb;
        float ls = 0.f;
        #pragma unroll
        for (int j = 0; j < 8; ++j) {
            const int e = j * 64 + lane;       // float4 units, 0..511
            const int idx = idxs[wave][e >> 4];
            float4 q  = e4[idx * 16 + (e & 15)];
            float4 xr = x4[e];
            q4[e] = q;
            float dx = q.x - xr.x, dy = q.y - xr.y;
            float dz = q.z - xr.z, dw = q.w - xr.w;
            ls = fmaf(dx, dx, ls); ls = fmaf(dy, dy, ls);
            ls = fmaf(dz, dz, ls); ls = fmaf(dw, dw, ls);
        }
        #pragma unroll
        for (int off = 32; off > 0; off >>= 1)
            ls += __shfl_down(ls, off, 64);
        if (lane == 0) wsum[wave] = ls;
    }
    __syncthreads();

    // ---- loss: block partial -> device atomic; ticketed last block finishes
    if (tid == 0) {
        double s = 0.0;
        #pragma unroll
        for (int w = 0; w < 16; ++w) s += (double)wsum[w];
        atomicAdd(lacc, s);
        __threadfence();
        unsigned tk = atomicAdd(cnt, 1u);
        if (tk == 255u) {
            double tot = atomicAdd(lacc, 0.0);   // all 256 adds complete
            qout[VQ_OUTQ] = (float)(1.25 * tot / 8388608.0);
        }
    }
}

extern "C" void kernel_launch(void* const* d_in, const int* in_sizes, int n_in,
                              void* d_out, int out_size, void* d_ws, size_t ws_size,
                              hipStream_t stream)
{
    const float* x   = (const float*)d_in[0];
    const float* emb = (const float*)d_in[1];
    float* out = (float*)d_out;

    short8* frag = (short8*)d_ws;                            // 65536 B
    float*  ctab = (float*)((char*)d_ws + 65536);            // 2048 B
    double* lacc = (double*)((char*)d_ws + 65536 + 2048);    // 8 B
    unsigned* cnt = (unsigned*)((char*)d_ws + 65536 + 2064); // 4 B

    vq_prep<<<dim3(16), dim3(256), 0, stream>>>(emb, frag, ctab, lacc, cnt);
    vq_main<<<dim3(256), dim3(1024), 0, stream>>>(x, emb, frag, ctab, out, lacc, cnt);
}